// Round 1
// baseline (131.242 us; speedup 1.0000x reference)
//
#include <hip/hip_runtime.h>
#include <math.h>

#define HH 496
#define WW 496
#define HWSZ (HH*WW)
#define NW 31
#define NWIN (NW*NW)   // 961

__constant__ float c_thetas[8] = {
    0.39269908169872414f, 0.7853981633974483f, 1.1780972450961724f,
    1.5707963267948966f,  1.9634954084936207f, 2.356194490192345f,
    2.748893571891069f,   3.141592653589793f};

// ---- Kernel 1: build the 72x5x5 Gabor bank (1800 floats) ----
__global__ void bank_kernel(const float* __restrict__ sigmas,
                            const float* __restrict__ lambdas,
                            float* __restrict__ filt) {
    int idx = threadIdx.x + blockIdx.x * blockDim.x;
    if (idx >= 72 * 25) return;
    int f = idx / 25, k = idx % 25;
    int dy = k / 5, dx = k % 5;
    int s = f / 24, rem = f % 24, l = rem / 8, t = rem % 8;
    float sig = sigmas[s], lam = lambdas[l], th = c_thetas[t];
    float y = (float)dy - 2.0f, x = (float)dx - 2.0f;
    float st = sinf(th), ct = cosf(th);
    float yt = -x * st + y * ct;
    float xt =  x * ct + y * st;
    float sx2 = sig * sig;          // sigma_x = sig
    float sy2 = 4.0f * sig * sig;   // sigma_y = sig/0.5
    float g = expf(-0.5f * (xt * xt / sx2 + yt * yt / sy2)) *
              cosf(6.28318530717958647692f * xt / lam + 1.5707963267948966f);
    filt[idx] = g;
}

// ---- Kernel 2: conv + max over 8 thetas -> out[9][496][496], block partial sums ----
__global__ __launch_bounds__(256) void conv_kernel(
    const float* __restrict__ img, const float* __restrict__ filt,
    float* __restrict__ out, float* __restrict__ partial) {
    __shared__ float tile[20 * 20];
    __shared__ float red[4];
    int tid = threadIdx.x;
    int tx = tid & 15, ty = tid >> 4;
    int bx = blockIdx.x, by = blockIdx.y;

    for (int i = tid; i < 400; i += 256) {
        int tY = i / 20, tX = i % 20;
        int gy = by * 16 + tY - 2, gx = bx * 16 + tX - 2;
        float v = 0.0f;
        if (gy >= 0 && gy < HH && gx >= 0 && gx < WW) v = img[gy * WW + gx];
        tile[i] = v;
    }
    __syncthreads();

    float r[25];
#pragma unroll
    for (int dy = 0; dy < 5; dy++)
#pragma unroll
        for (int dx = 0; dx < 5; dx++)
            r[dy * 5 + dx] = tile[(ty + dy) * 20 + (tx + dx)];

    int y = by * 16 + ty, x = bx * 16 + tx;

    for (int c = 0; c < 9; c++) {
        float maxv = -3.402823466e38f;
#pragma unroll
        for (int t = 0; t < 8; t++) {
            const float* fp = filt + (c * 8 + t) * 25;  // wave-uniform -> s_load
            float acc = 0.0f;
#pragma unroll
            for (int k = 0; k < 25; k++) acc += r[k] * fp[k];
            maxv = fmaxf(maxv, acc);
        }
        out[c * HWSZ + y * WW + x] = maxv;

        // deterministic block sum for the channel mean
        float s = maxv;
#pragma unroll
        for (int off = 32; off > 0; off >>= 1) s += __shfl_down(s, off, 64);
        if ((tid & 63) == 0) red[tid >> 6] = s;
        __syncthreads();
        if (tid == 0)
            partial[(by * NW + bx) * 9 + c] = red[0] + red[1] + red[2] + red[3];
        __syncthreads();
    }
}

// ---- Kernel 3: reduce partials -> mean[9] ----
__global__ void mean_kernel(const float* __restrict__ partial,
                            float* __restrict__ mean) {
    __shared__ float red[256];
    int tid = threadIdx.x;
    for (int c = 0; c < 9; c++) {
        float s = 0.0f;
        for (int i = tid; i < NWIN; i += 256) s += partial[i * 9 + c];
        red[tid] = s;
        __syncthreads();
        for (int off = 128; off > 0; off >>= 1) {
            if (tid < off) red[tid] += red[tid + off];
            __syncthreads();
        }
        if (tid == 0) mean[c] = red[0] * (1.0f / (float)HWSZ);
        __syncthreads();
    }
}

// ---- Kernel 4: per-window keypoint test + patch extraction ----
__global__ __launch_bounds__(256) void patch_kernel(
    const float* __restrict__ out, const float* __restrict__ mean,
    float* __restrict__ dst) {
    int w = blockIdx.x;
    int r = w / NW, cl = w % NW;
    int tid = threadIdx.x;
    int wy = tid >> 4, wx = tid & 15;
    __shared__ float centerv;

    // Stage 1: valid_kp = OR over channels of (argmax of thresholded 16x16 window == 128)
    bool valid = false;
    for (int c = 0; c < 9; c++) {
        float v = out[c * HWSZ + (r * 16 + wy) * WW + (cl * 16 + wx)];
        float m5 = mean[c] * 5.0f;
        float thr = (v > m5) ? v : 0.0f;
        if (tid == 128) centerv = thr;
        __syncthreads();
        float cv = centerv;
        // first-occurrence argmax semantics: center must beat all earlier strictly,
        // all later non-strictly
        bool ok = (tid < 128) ? (thr < cv) : ((tid > 128) ? (thr <= cv) : true);
        int all = __syncthreads_and(ok ? 1 : 0);  // barrier: safe to reuse centerv
        if (all) valid = true;
    }

    // Stage 2: 9 patches of 32x32, masked by (valid && any-nonzero)
    for (int c = 0; c < 9; c++) {
        float vals[4];
        bool nzl = false;
#pragma unroll
        for (int q = 0; q < 4; q++) {
            int e = q * 256 + tid;
            int i = e >> 5, j = e & 31;
            int row = r * 16 + i - 8;   // padded coord minus 16
            int col = cl * 16 + j - 8;
            float v = 0.0f;
            if (row >= 0 && row < HH && col >= 0 && col < WW)
                v = out[c * HWSZ + row * WW + col];
            vals[q] = v;
            nzl = nzl || (v != 0.0f);
        }
        int nz = __syncthreads_or(nzl ? 1 : 0);
        float mk = (valid && nz) ? 1.0f : 0.0f;
#pragma unroll
        for (int q = 0; q < 4; q++) {
            int e = q * 256 + tid;
            dst[(size_t)c * NWIN * 1024 + (size_t)w * 1024 + e] = vals[q] * mk;
        }
    }
}

extern "C" void kernel_launch(void* const* d_in, const int* in_sizes, int n_in,
                              void* d_out, int out_size, void* d_ws, size_t ws_size,
                              hipStream_t stream) {
    const float* img     = (const float*)d_in[0];
    const float* sigmas  = (const float*)d_in[1];
    const float* lambdas = (const float*)d_in[2];
    float* ws = (float*)d_ws;
    // ws layout (floats): filt[1800] @0, partial[8649] @2048, mean[9] @11008, out @11264
    float* filt    = ws;
    float* partial = ws + 2048;
    float* meanp   = ws + 11008;
    float* outb    = ws + 11264;   // 9*496*496 = 2,214,144 floats (~8.5 MiB total ws)

    bank_kernel<<<8, 256, 0, stream>>>(sigmas, lambdas, filt);
    conv_kernel<<<dim3(NW, NW), 256, 0, stream>>>(img, filt, outb, partial);
    mean_kernel<<<1, 256, 0, stream>>>(partial, meanp);
    patch_kernel<<<NWIN, 256, 0, stream>>>(outb, meanp, (float*)d_out);
}